// Round 14
// baseline (109.589 us; speedup 1.0000x reference)
//
#include <hip/hip_runtime.h>
#include <hip/hip_bf16.h>

constexpr int N_NODES = 100000;
constexpr int DIM     = 128;
constexpr int N_EDGES = 640000;

constexpr int CHUNK     = 1024;
constexpr int N_CHUNKS  = (N_NODES + CHUNK - 1) / CHUNK;   // 98
constexpr int BINCAP    = 8192;                            // stage capacity (unpadded)
constexpr int CSRCAP    = 12288;                           // padded csr region per chunk
constexpr int EPB       = 1024;                            // edges per bin block
constexpr int SRC_BITS  = 17;
constexpr int SRC_MASK  = (1 << SRC_BITS) - 1;

constexpr int YNB         = 32;                            // nodes per gemm block
constexpr int GEMM_BLOCKS = N_NODES / YNB;                 // 3125
constexpr int BIN_BLOCKS  = N_EDGES / EPB;                 // 625
constexpr int DSTRIDE     = 640;                           // descriptor row stride

typedef __attribute__((ext_vector_type(4))) float        f32x4;
typedef __attribute__((ext_vector_type(8))) short        bf16x8;
typedef __attribute__((ext_vector_type(4))) unsigned int u32x4;
typedef __attribute__((ext_vector_type(4))) int          i32x4;

static __device__ inline unsigned short f2bf(float f) {
    __hip_bfloat16 h = __float2bfloat16(f);   // RNE
    return *reinterpret_cast<unsigned short*>(&h);
}
static __device__ inline float bf_lo(unsigned u) { return __uint_as_float(u << 16); }
static __device__ inline float bf_hi(unsigned u) { return __uint_as_float(u & 0xffff0000u); }

static __device__ inline bf16x8 pack8(f32x4 a, f32x4 b) {
    bf16x8 v;
    v[0] = (short)f2bf(a.x); v[1] = (short)f2bf(a.y);
    v[2] = (short)f2bf(a.z); v[3] = (short)f2bf(a.w);
    v[4] = (short)f2bf(b.x); v[5] = (short)f2bf(b.y);
    v[6] = (short)f2bf(b.z); v[7] = (short)f2bf(b.w);
    return v;
}

// ---------------------------------------------------------------------------
// 1) FUSED: blocks [0,3125) dense GEMM y = bf16(x @ W^T);
//           blocks [3125,3750) deterministic edge binning.
//    x / edge loads are nontemporal (single-use) to preserve y's cacheability.
// ---------------------------------------------------------------------------
__global__ __launch_bounds__(256) void gcn_gemm_bin(
    const float* __restrict__ x,
    const float* __restrict__ W,
    const int* __restrict__ esrc,
    const int* __restrict__ edst,
    unsigned short* __restrict__ y,
    unsigned int* __restrict__ blkdata,   // [625][1024]
    int* __restrict__ bcnt,               // [98][640]
    int* __restrict__ bst)                // [98][640]
{
    __shared__ unsigned short wl[DIM][DIM + 8];   // gemm path (34.8 KB)
    __shared__ int bh[N_CHUNKS];                  // bin path
    __shared__ int bpre[128];

    const int tid = threadIdx.x;

    if (blockIdx.x >= GEMM_BLOCKS) {
        // ---------------- bin path ----------------
        const int b  = blockIdx.x - GEMM_BLOCKS;
        const int e0 = b * EPB + tid * 4;

        if (tid < N_CHUNKS) bh[tid] = 0;
        __syncthreads();

        const i32x4 s4 = __builtin_nontemporal_load(
            reinterpret_cast<const i32x4*>(esrc + e0));
        const i32x4 d4 = __builtin_nontemporal_load(
            reinterpret_cast<const i32x4*>(edst + e0));
        const int ds[4] = {d4.x, d4.y, d4.z, d4.w};
        const int ss[4] = {s4.x, s4.y, s4.z, s4.w};

        int bin[4], pos[4];
        unsigned pv[4];
        #pragma unroll
        for (int q = 0; q < 4; ++q) {
            bin[q] = ds[q] >> 10;
            pv[q]  = (unsigned)ss[q] | ((unsigned)(ds[q] & (CHUNK - 1)) << SRC_BITS);
            pos[q] = atomicAdd(&bh[bin[q]], 1);
        }
        __syncthreads();

        if (tid < 128) bpre[tid] = (tid < N_CHUNKS) ? bh[tid] : 0;
        __syncthreads();
        for (int d = 1; d < 128; d <<= 1) {
            int add = 0;
            if (tid < 128 && tid >= d) add = bpre[tid - d];
            __syncthreads();
            if (tid < 128) bpre[tid] += add;
            __syncthreads();
        }
        if (tid < N_CHUNKS) {
            bcnt[tid * DSTRIDE + b] = bh[tid];
            bst [tid * DSTRIDE + b] = (tid > 0) ? bpre[tid - 1] : 0;
        }
        __syncthreads();

        #pragma unroll
        for (int q = 0; q < 4; ++q) {
            const int excl = (bin[q] > 0) ? bpre[bin[q] - 1] : 0;
            blkdata[(size_t)b * EPB + excl + pos[q]] = pv[q];
        }
        return;
    }

    // ---------------- gemm path ----------------
    const int n0 = blockIdx.x * YNB;

    #pragma unroll
    for (int rep = 0; rep < 8; ++rep) {
        const int e   = rep * 2048 + tid * 8;
        const int row = e >> 7;
        const int col = e & 127;
        f32x4 a = *reinterpret_cast<const f32x4*>(W + e);
        f32x4 b = *reinterpret_cast<const f32x4*>(W + e + 4);
        *reinterpret_cast<bf16x8*>(&wl[row][col]) = pack8(a, b);
    }
    __syncthreads();

    const int w    = tid >> 6;
    const int lane = tid & 63;
    const int r    = lane & 15;
    const int g    = lane >> 4;
    const int rowt  = w & 1;
    const int cbase = 4 * (w >> 1);

    bf16x8 af[4];
    #pragma unroll
    for (int t = 0; t < 4; ++t) {
        const float* xp = x + (size_t)(n0 + 16 * rowt + r) * DIM + 32 * t + 8 * g;
        f32x4 a = __builtin_nontemporal_load(reinterpret_cast<const f32x4*>(xp));
        f32x4 b = __builtin_nontemporal_load(reinterpret_cast<const f32x4*>(xp) + 1);
        af[t] = pack8(a, b);
    }

    #pragma unroll
    for (int cc = 0; cc < 4; ++cc) {
        const int c = cbase + cc;
        f32x4 acc = {0.f, 0.f, 0.f, 0.f};
        #pragma unroll
        for (int t = 0; t < 4; ++t) {
            bf16x8 wf = *reinterpret_cast<const bf16x8*>(&wl[16 * c + r][32 * t + 8 * g]);
            acc = __builtin_amdgcn_mfma_f32_16x16x32_bf16(af[t], wf, acc, 0, 0, 0);
        }
        #pragma unroll
        for (int q = 0; q < 4; ++q)
            y[(size_t)(n0 + 16 * rowt + 4 * g + q) * DIM + 16 * c + r] =
                f2bf(acc[q]);
    }
}

// ---------------------------------------------------------------------------
// 2) Build: one block per chunk. Parallel run-compaction via LDS binary
//    search, per-node hist + scan (PADDED to multiple of 4), dense scatter
//    -> csr, pad slots filled with the node's own id.
//    off[n] = padded_start(14b) | true_count << 14.
// ---------------------------------------------------------------------------
__global__ __launch_bounds__(256) void gcn_build(
    const unsigned int* __restrict__ blkdata,
    const int* __restrict__ bcnt,
    const int* __restrict__ bst,
    unsigned int* __restrict__ csr,       // [98][12288]
    int* __restrict__ off)
{
    __shared__ unsigned stage[BINCAP];    // 32 KB
    __shared__ int hist[CHUNK];           // 4 KB
    __shared__ int s[256];                // 1 KB
    __shared__ int rpre[BIN_BLOCKS];      // 2.5 KB
    __shared__ int rbase[BIN_BLOCKS];     // 2.5 KB

    const int c = blockIdx.x;
    const int t = threadIdx.x;

    #pragma unroll
    for (int q = 0; q < 4; ++q) hist[t + 256 * q] = 0;

    // scan the 625 per-block counts (3 per thread)
    const int base = t * 3;
    int v0 = (base + 0 < BIN_BLOCKS) ? bcnt[c * DSTRIDE + base + 0] : 0;
    int v1 = (base + 1 < BIN_BLOCKS) ? bcnt[c * DSTRIDE + base + 1] : 0;
    int v2 = (base + 2 < BIN_BLOCKS) ? bcnt[c * DSTRIDE + base + 2] : 0;

    s[t] = v0 + v1 + v2;
    __syncthreads();
    for (int d = 1; d < 256; d <<= 1) {
        int add = (t >= d) ? s[t - d] : 0;
        __syncthreads();
        s[t] += add;
        __syncthreads();
    }
    const int nb   = min(s[255], BINCAP);
    const int excl = (t > 0) ? s[t - 1] : 0;

    if (base + 0 < BIN_BLOCKS) {
        rpre [base + 0] = excl;
        rbase[base + 0] = (base + 0) * EPB + bst[c * DSTRIDE + base + 0];
    }
    if (base + 1 < BIN_BLOCKS) {
        rpre [base + 1] = excl + v0;
        rbase[base + 1] = (base + 1) * EPB + bst[c * DSTRIDE + base + 1];
    }
    if (base + 2 < BIN_BLOCKS) {
        rpre [base + 2] = excl + v0 + v1;
        rbase[base + 2] = (base + 2) * EPB + bst[c * DSTRIDE + base + 2];
    }
    __syncthreads();

    // parallel compaction: binary search the owning run for each stage slot
    for (int e = t; e < nb; e += 256) {
        int lo = 0, hi = BIN_BLOCKS - 1;
        while (lo < hi) {
            int mid = (lo + hi + 1) >> 1;
            if (rpre[mid] <= e) lo = mid; else hi = mid - 1;
        }
        stage[e] = blkdata[rbase[lo] + (e - rpre[lo])];
    }
    __syncthreads();

    for (int e = t; e < nb; e += 256)
        atomicAdd(&hist[stage[e] >> SRC_BITS], 1);
    __syncthreads();

    const int h0 = hist[4 * t + 0], h1 = hist[4 * t + 1];
    const int h2 = hist[4 * t + 2], h3 = hist[4 * t + 3];
    const int p0 = (h0 + 3) & ~3, p1 = (h1 + 3) & ~3;
    const int p2 = (h2 + 3) & ~3, p3 = (h3 + 3) & ~3;

    s[t] = p0 + p1 + p2 + p3;
    __syncthreads();
    for (int d = 1; d < 256; d <<= 1) {
        int add = (t >= d) ? s[t - d] : 0;
        __syncthreads();
        s[t] += add;
        __syncthreads();
    }
    const int nexcl = (t > 0) ? s[t - 1] : 0;

    const int st0 = nexcl;
    const int st1 = st0 + p0;
    const int st2 = st1 + p1;
    const int st3 = st2 + p2;
    hist[4 * t + 0] = st0;  hist[4 * t + 1] = st1;
    hist[4 * t + 2] = st2;  hist[4 * t + 3] = st3;

    const int nbase = c * CHUNK;
    if (nbase + 4 * t + 0 < N_NODES) off[nbase + 4 * t + 0] = st0 | (h0 << 14);
    if (nbase + 4 * t + 1 < N_NODES) off[nbase + 4 * t + 1] = st1 | (h1 << 14);
    if (nbase + 4 * t + 2 < N_NODES) off[nbase + 4 * t + 2] = st2 | (h2 << 14);
    if (nbase + 4 * t + 3 < N_NODES) off[nbase + 4 * t + 3] = st3 | (h3 << 14);
    __syncthreads();

    unsigned int* creg = csr + (size_t)c * CSRCAP;
    for (int e = t; e < nb; e += 256) {
        unsigned v = stage[e];
        int slot   = atomicAdd(&hist[v >> SRC_BITS], 1);
        creg[slot] = v & SRC_MASK;
    }

    // padding fill: slots [st+h, st+p) get the node's own global id
    {
        const int sts[4] = {st0, st1, st2, st3};
        const int hs[4]  = {h0, h1, h2, h3};
        const int ps[4]  = {p0, p1, p2, p3};
        #pragma unroll
        for (int j = 0; j < 4; ++j) {
            const unsigned gn = (unsigned)(nbase + 4 * t + j);
            for (int k = sts[j] + hs[j]; k < sts[j] + ps[j]; ++k)
                creg[k] = gn;
        }
    }
}

// ---------------------------------------------------------------------------
// 3) Gather in y-space, tail-free: every run is a multiple of 4 entries
//    (pad entries = own node id, corrected by yscale = 1 - pad*inv).
//    out[n] = relu( acc*inv + yscale*y[n] + b ), nontemporal out stores.
// ---------------------------------------------------------------------------
static __device__ inline void acc8(float* acc, u32x4 v) {
    #pragma unroll
    for (int q = 0; q < 4; ++q) {
        unsigned u = v[q];
        acc[2 * q]     += bf_lo(u);
        acc[2 * q + 1] += bf_hi(u);
    }
}

__global__ __launch_bounds__(256) void gcn_agg(
    const unsigned short* __restrict__ y,
    const int* __restrict__ off,
    const unsigned int* __restrict__ csr,
    const float* __restrict__ bias,
    float* __restrict__ out)
{
    const int tid    = threadIdx.x;
    const int lane16 = tid & 15;
    const int n      = blockIdx.x * 16 + (tid >> 4);   // grid exact: 6250
    const int col8   = lane16 * 8;

    const int meta   = off[n];
    const int count  = meta >> 14;
    const int start  = (n >> 10) * CSRCAP + (meta & 16383);
    const int padded = (count + 3) & ~3;
    const int end    = start + padded;

    float acc[8];
    #pragma unroll
    for (int q = 0; q < 8; ++q) acc[q] = 0.0f;

    for (int i = start; i < end; i += 4) {
        const i32x4 i4 = *reinterpret_cast<const i32x4*>(csr + i);   // 16B-aligned
        u32x4 v0 = *reinterpret_cast<const u32x4*>(y + (size_t)i4.x * DIM + col8);
        u32x4 v1 = *reinterpret_cast<const u32x4*>(y + (size_t)i4.y * DIM + col8);
        u32x4 v2 = *reinterpret_cast<const u32x4*>(y + (size_t)i4.z * DIM + col8);
        u32x4 v3 = *reinterpret_cast<const u32x4*>(y + (size_t)i4.w * DIM + col8);
        acc8(acc, v0); acc8(acc, v1); acc8(acc, v2); acc8(acc, v3);
    }

    const float inv    = 1.0f / fmaxf((float)count, 1.0f);
    const float yscale = 1.0f - (float)(padded - count) * inv;
    const u32x4 yr = *reinterpret_cast<const u32x4*>(y + (size_t)n * DIM + col8);
    const f32x4 b0 = *reinterpret_cast<const f32x4*>(bias + col8);
    const f32x4 b1 = *reinterpret_cast<const f32x4*>(bias + col8 + 4);

    f32x4 o0, o1;
    o0.x = fmaxf(acc[0] * inv + yscale * bf_lo(yr[0]) + b0.x, 0.0f);
    o0.y = fmaxf(acc[1] * inv + yscale * bf_hi(yr[0]) + b0.y, 0.0f);
    o0.z = fmaxf(acc[2] * inv + yscale * bf_lo(yr[1]) + b0.z, 0.0f);
    o0.w = fmaxf(acc[3] * inv + yscale * bf_hi(yr[1]) + b0.w, 0.0f);
    o1.x = fmaxf(acc[4] * inv + yscale * bf_lo(yr[2]) + b1.x, 0.0f);
    o1.y = fmaxf(acc[5] * inv + yscale * bf_hi(yr[2]) + b1.y, 0.0f);
    o1.z = fmaxf(acc[6] * inv + yscale * bf_lo(yr[3]) + b1.z, 0.0f);
    o1.w = fmaxf(acc[7] * inv + yscale * bf_hi(yr[3]) + b1.w, 0.0f);

    __builtin_nontemporal_store(o0, reinterpret_cast<f32x4*>(out + (size_t)n * DIM + col8));
    __builtin_nontemporal_store(o1, reinterpret_cast<f32x4*>(out + (size_t)n * DIM + col8 + 4));
}

// ---------------------------------------------------------------------------
extern "C" void kernel_launch(void* const* d_in, const int* in_sizes, int n_in,
                              void* d_out, int out_size, void* d_ws, size_t ws_size,
                              hipStream_t stream)
{
    const float* x    = (const float*)d_in[0];
    const int*   eidx = (const int*)d_in[1];
    const float* W    = (const float*)d_in[2];
    const float* bias = (const float*)d_in[3];
    float*       out  = (float*)d_out;

    const int* esrc = eidx;
    const int* edst = eidx + N_EDGES;

    int* bcnt             = (int*)d_ws;                                   // [98*640]
    int* bst              = bcnt + N_CHUNKS * DSTRIDE;                    // [98*640]
    unsigned int* blkdata = (unsigned int*)(bst + N_CHUNKS * DSTRIDE);    // [625*1024]
    unsigned int* csr     = blkdata + (size_t)BIN_BLOCKS * EPB;           // [98*12288]
    int* off              = (int*)(csr + (size_t)N_CHUNKS * CSRCAP);      // [100352]
    unsigned short* y     = (unsigned short*)(off + 100352);              // [N*128] bf16

    gcn_gemm_bin<<<GEMM_BLOCKS + BIN_BLOCKS, 256, 0, stream>>>(
        x, W, esrc, edst, y, blkdata, bcnt, bst);
    gcn_build<<<N_CHUNKS, 256, 0, stream>>>(blkdata, bcnt, bst, csr, off);
    gcn_agg  <<<N_NODES / 16, 256, 0, stream>>>(y, off, csr, bias, out);
}

// Round 15
// 99.809 us; speedup vs baseline: 1.0980x; 1.0980x over previous
//
#include <hip/hip_runtime.h>
#include <hip/hip_bf16.h>

constexpr int N_NODES = 100000;
constexpr int DIM     = 128;
constexpr int N_EDGES = 640000;

constexpr int CHUNK     = 1024;
constexpr int N_CHUNKS  = (N_NODES + CHUNK - 1) / CHUNK;   // 98
constexpr int BINCAP    = 8192;
constexpr int EPB       = 1024;                            // edges per bin block
constexpr int SRC_BITS  = 17;
constexpr int SRC_MASK  = (1 << SRC_BITS) - 1;

constexpr int YNB         = 32;                            // nodes per gemm block
constexpr int GEMM_BLOCKS = N_NODES / YNB;                 // 3125
constexpr int BIN_BLOCKS  = N_EDGES / EPB;                 // 625
constexpr int DSTRIDE     = 640;                           // descriptor row stride

typedef __attribute__((ext_vector_type(4))) float        f32x4;
typedef __attribute__((ext_vector_type(8))) short        bf16x8;
typedef __attribute__((ext_vector_type(4))) unsigned int u32x4;

static __device__ inline unsigned short f2bf(float f) {
    __hip_bfloat16 h = __float2bfloat16(f);   // RNE
    return *reinterpret_cast<unsigned short*>(&h);
}
static __device__ inline float bf_lo(unsigned u) { return __uint_as_float(u << 16); }
static __device__ inline float bf_hi(unsigned u) { return __uint_as_float(u & 0xffff0000u); }

static __device__ inline bf16x8 pack8(f32x4 a, f32x4 b) {
    bf16x8 v;
    v[0] = (short)f2bf(a.x); v[1] = (short)f2bf(a.y);
    v[2] = (short)f2bf(a.z); v[3] = (short)f2bf(a.w);
    v[4] = (short)f2bf(b.x); v[5] = (short)f2bf(b.y);
    v[6] = (short)f2bf(b.z); v[7] = (short)f2bf(b.w);
    return v;
}

// ---------------------------------------------------------------------------
// 1) FUSED: blocks [0,3125) dense GEMM y = bf16(x @ W^T);
//           blocks [3125,3750) deterministic edge binning (plain loads).
// ---------------------------------------------------------------------------
__global__ __launch_bounds__(256) void gcn_gemm_bin(
    const float* __restrict__ x,
    const float* __restrict__ W,
    const int* __restrict__ esrc,
    const int* __restrict__ edst,
    unsigned short* __restrict__ y,
    unsigned int* __restrict__ blkdata,   // [625][1024]
    int* __restrict__ bcnt,               // [98][640]
    int* __restrict__ bst)                // [98][640]
{
    __shared__ unsigned short wl[DIM][DIM + 8];   // gemm path (34.8 KB)
    __shared__ int bh[N_CHUNKS];                  // bin path
    __shared__ int bpre[128];

    const int tid = threadIdx.x;

    if (blockIdx.x >= GEMM_BLOCKS) {
        // ---------------- bin path ----------------
        const int b  = blockIdx.x - GEMM_BLOCKS;
        const int e0 = b * EPB + tid * 4;

        if (tid < N_CHUNKS) bh[tid] = 0;
        __syncthreads();

        const int4 s4 = *reinterpret_cast<const int4*>(esrc + e0);
        const int4 d4 = *reinterpret_cast<const int4*>(edst + e0);
        const int ds[4] = {d4.x, d4.y, d4.z, d4.w};
        const int ss[4] = {s4.x, s4.y, s4.z, s4.w};

        int bin[4], pos[4];
        unsigned pv[4];
        #pragma unroll
        for (int q = 0; q < 4; ++q) {
            bin[q] = ds[q] >> 10;
            pv[q]  = (unsigned)ss[q] | ((unsigned)(ds[q] & (CHUNK - 1)) << SRC_BITS);
            pos[q] = atomicAdd(&bh[bin[q]], 1);
        }
        __syncthreads();

        if (tid < 128) bpre[tid] = (tid < N_CHUNKS) ? bh[tid] : 0;
        __syncthreads();
        for (int d = 1; d < 128; d <<= 1) {
            int add = 0;
            if (tid < 128 && tid >= d) add = bpre[tid - d];
            __syncthreads();
            if (tid < 128) bpre[tid] += add;
            __syncthreads();
        }
        if (tid < N_CHUNKS) {
            bcnt[tid * DSTRIDE + b] = bh[tid];
            bst [tid * DSTRIDE + b] = (tid > 0) ? bpre[tid - 1] : 0;
        }
        __syncthreads();

        #pragma unroll
        for (int q = 0; q < 4; ++q) {
            const int excl = (bin[q] > 0) ? bpre[bin[q] - 1] : 0;
            blkdata[(size_t)b * EPB + excl + pos[q]] = pv[q];
        }
        return;
    }

    // ---------------- gemm path ----------------
    const int n0 = blockIdx.x * YNB;

    #pragma unroll
    for (int rep = 0; rep < 8; ++rep) {
        const int e   = rep * 2048 + tid * 8;
        const int row = e >> 7;
        const int col = e & 127;
        f32x4 a = *reinterpret_cast<const f32x4*>(W + e);
        f32x4 b = *reinterpret_cast<const f32x4*>(W + e + 4);
        *reinterpret_cast<bf16x8*>(&wl[row][col]) = pack8(a, b);
    }
    __syncthreads();

    const int w    = tid >> 6;
    const int lane = tid & 63;
    const int r    = lane & 15;
    const int g    = lane >> 4;
    const int rowt  = w & 1;
    const int cbase = 4 * (w >> 1);

    bf16x8 af[4];
    #pragma unroll
    for (int t = 0; t < 4; ++t) {
        const float* xp = x + (size_t)(n0 + 16 * rowt + r) * DIM + 32 * t + 8 * g;
        f32x4 a = *reinterpret_cast<const f32x4*>(xp);
        f32x4 b = *reinterpret_cast<const f32x4*>(xp + 4);
        af[t] = pack8(a, b);
    }

    #pragma unroll
    for (int cc = 0; cc < 4; ++cc) {
        const int c = cbase + cc;
        f32x4 acc = {0.f, 0.f, 0.f, 0.f};
        #pragma unroll
        for (int t = 0; t < 4; ++t) {
            bf16x8 wf = *reinterpret_cast<const bf16x8*>(&wl[16 * c + r][32 * t + 8 * g]);
            acc = __builtin_amdgcn_mfma_f32_16x16x32_bf16(af[t], wf, acc, 0, 0, 0);
        }
        #pragma unroll
        for (int q = 0; q < 4; ++q)
            y[(size_t)(n0 + 16 * rowt + 4 * g + q) * DIM + 16 * c + r] =
                f2bf(acc[q]);
    }
}

// ---------------------------------------------------------------------------
// 2) Build: one block per chunk. PARALLEL run-compaction (LDS binary search),
//    per-node hist + scan, dense scatter -> csr.
//    off[n] = start(13b) | true_count << 13.   (no padding)
// ---------------------------------------------------------------------------
__global__ __launch_bounds__(256) void gcn_build(
    const unsigned int* __restrict__ blkdata,
    const int* __restrict__ bcnt,
    const int* __restrict__ bst,
    unsigned int* __restrict__ csr,       // [98][8192]
    int* __restrict__ off)
{
    __shared__ unsigned stage[BINCAP];    // 32 KB
    __shared__ int hist[CHUNK];           // 4 KB
    __shared__ int s[256];                // 1 KB
    __shared__ int rpre[BIN_BLOCKS];      // 2.5 KB
    __shared__ int rbase[BIN_BLOCKS];     // 2.5 KB

    const int c = blockIdx.x;
    const int t = threadIdx.x;

    #pragma unroll
    for (int q = 0; q < 4; ++q) hist[t + 256 * q] = 0;

    // scan the 625 per-block counts (3 per thread)
    const int base = t * 3;
    int v0 = (base + 0 < BIN_BLOCKS) ? bcnt[c * DSTRIDE + base + 0] : 0;
    int v1 = (base + 1 < BIN_BLOCKS) ? bcnt[c * DSTRIDE + base + 1] : 0;
    int v2 = (base + 2 < BIN_BLOCKS) ? bcnt[c * DSTRIDE + base + 2] : 0;

    s[t] = v0 + v1 + v2;
    __syncthreads();
    for (int d = 1; d < 256; d <<= 1) {
        int add = (t >= d) ? s[t - d] : 0;
        __syncthreads();
        s[t] += add;
        __syncthreads();
    }
    const int nb   = min(s[255], BINCAP);
    const int excl = (t > 0) ? s[t - 1] : 0;

    if (base + 0 < BIN_BLOCKS) {
        rpre [base + 0] = excl;
        rbase[base + 0] = (base + 0) * EPB + bst[c * DSTRIDE + base + 0];
    }
    if (base + 1 < BIN_BLOCKS) {
        rpre [base + 1] = excl + v0;
        rbase[base + 1] = (base + 1) * EPB + bst[c * DSTRIDE + base + 1];
    }
    if (base + 2 < BIN_BLOCKS) {
        rpre [base + 2] = excl + v0 + v1;
        rbase[base + 2] = (base + 2) * EPB + bst[c * DSTRIDE + base + 2];
    }
    __syncthreads();

    // parallel compaction: binary search the owning run for each stage slot
    for (int e = t; e < nb; e += 256) {
        int lo = 0, hi = BIN_BLOCKS - 1;
        while (lo < hi) {
            int mid = (lo + hi + 1) >> 1;
            if (rpre[mid] <= e) lo = mid; else hi = mid - 1;
        }
        stage[e] = blkdata[rbase[lo] + (e - rpre[lo])];
    }
    __syncthreads();

    for (int e = t; e < nb; e += 256)
        atomicAdd(&hist[stage[e] >> SRC_BITS], 1);
    __syncthreads();

    const int h0 = hist[4 * t + 0], h1 = hist[4 * t + 1];
    const int h2 = hist[4 * t + 2], h3 = hist[4 * t + 3];

    s[t] = h0 + h1 + h2 + h3;
    __syncthreads();
    for (int d = 1; d < 256; d <<= 1) {
        int add = (t >= d) ? s[t - d] : 0;
        __syncthreads();
        s[t] += add;
        __syncthreads();
    }
    const int nexcl = (t > 0) ? s[t - 1] : 0;

    const int st0 = nexcl;
    const int st1 = st0 + h0;
    const int st2 = st1 + h1;
    const int st3 = st2 + h2;
    hist[4 * t + 0] = st0;  hist[4 * t + 1] = st1;
    hist[4 * t + 2] = st2;  hist[4 * t + 3] = st3;

    const int nbase = c * CHUNK;
    if (nbase + 4 * t + 0 < N_NODES) off[nbase + 4 * t + 0] = st0 | (h0 << 13);
    if (nbase + 4 * t + 1 < N_NODES) off[nbase + 4 * t + 1] = st1 | (h1 << 13);
    if (nbase + 4 * t + 2 < N_NODES) off[nbase + 4 * t + 2] = st2 | (h2 << 13);
    if (nbase + 4 * t + 3 < N_NODES) off[nbase + 4 * t + 3] = st3 | (h3 << 13);
    __syncthreads();

    unsigned int* creg = csr + (size_t)c * BINCAP;
    for (int e = t; e < nb; e += 256) {
        unsigned v = stage[e];
        int slot   = atomicAdd(&hist[v >> SRC_BITS], 1);
        creg[slot] = v & SRC_MASK;
    }
}

// ---------------------------------------------------------------------------
// 3) Gather in y-space (exactly R11's shape):
//    out[n] = relu( sum(y[src])/max(deg,1) + y[n] + b ).
//    16 lanes/node, 16B/lane, 4-deep unroll + remainder, plain stores.
// ---------------------------------------------------------------------------
static __device__ inline void acc8(float* acc, u32x4 v) {
    #pragma unroll
    for (int q = 0; q < 4; ++q) {
        unsigned u = v[q];
        acc[2 * q]     += bf_lo(u);
        acc[2 * q + 1] += bf_hi(u);
    }
}

__global__ __launch_bounds__(256) void gcn_agg(
    const unsigned short* __restrict__ y,
    const int* __restrict__ off,
    const unsigned int* __restrict__ csr,
    const float* __restrict__ bias,
    float* __restrict__ out)
{
    const int tid    = threadIdx.x;
    const int lane16 = tid & 15;
    const int n      = blockIdx.x * 16 + (tid >> 4);   // grid exact: 6250
    const int col8   = lane16 * 8;

    const int meta  = off[n];
    const int count = meta >> 13;
    int i           = (n >> 10) * BINCAP + (meta & (BINCAP - 1));
    const int end   = i + count;

    float acc[8];
    #pragma unroll
    for (int q = 0; q < 8; ++q) acc[q] = 0.0f;

    for (; i + 4 <= end; i += 4) {
        int s0 = csr[i], s1 = csr[i + 1], s2 = csr[i + 2], s3 = csr[i + 3];
        u32x4 v0 = *reinterpret_cast<const u32x4*>(y + (size_t)s0 * DIM + col8);
        u32x4 v1 = *reinterpret_cast<const u32x4*>(y + (size_t)s1 * DIM + col8);
        u32x4 v2 = *reinterpret_cast<const u32x4*>(y + (size_t)s2 * DIM + col8);
        u32x4 v3 = *reinterpret_cast<const u32x4*>(y + (size_t)s3 * DIM + col8);
        acc8(acc, v0); acc8(acc, v1); acc8(acc, v2); acc8(acc, v3);
    }
    for (; i < end; ++i) {
        u32x4 v = *reinterpret_cast<const u32x4*>(y + (size_t)csr[i] * DIM + col8);
        acc8(acc, v);
    }

    const float inv = 1.0f / fmaxf((float)count, 1.0f);
    const u32x4 yr = *reinterpret_cast<const u32x4*>(y + (size_t)n * DIM + col8);
    const f32x4 b0 = *reinterpret_cast<const f32x4*>(bias + col8);
    const f32x4 b1 = *reinterpret_cast<const f32x4*>(bias + col8 + 4);

    f32x4 o0, o1;
    o0.x = fmaxf(acc[0] * inv + bf_lo(yr[0]) + b0.x, 0.0f);
    o0.y = fmaxf(acc[1] * inv + bf_hi(yr[0]) + b0.y, 0.0f);
    o0.z = fmaxf(acc[2] * inv + bf_lo(yr[1]) + b0.z, 0.0f);
    o0.w = fmaxf(acc[3] * inv + bf_hi(yr[1]) + b0.w, 0.0f);
    o1.x = fmaxf(acc[4] * inv + bf_lo(yr[2]) + b1.x, 0.0f);
    o1.y = fmaxf(acc[5] * inv + bf_hi(yr[2]) + b1.y, 0.0f);
    o1.z = fmaxf(acc[6] * inv + bf_lo(yr[3]) + b1.z, 0.0f);
    o1.w = fmaxf(acc[7] * inv + bf_hi(yr[3]) + b1.w, 0.0f);

    *reinterpret_cast<f32x4*>(out + (size_t)n * DIM + col8)     = o0;
    *reinterpret_cast<f32x4*>(out + (size_t)n * DIM + col8 + 4) = o1;
}

// ---------------------------------------------------------------------------
extern "C" void kernel_launch(void* const* d_in, const int* in_sizes, int n_in,
                              void* d_out, int out_size, void* d_ws, size_t ws_size,
                              hipStream_t stream)
{
    const float* x    = (const float*)d_in[0];
    const int*   eidx = (const int*)d_in[1];
    const float* W    = (const float*)d_in[2];
    const float* bias = (const float*)d_in[3];
    float*       out  = (float*)d_out;

    const int* esrc = eidx;
    const int* edst = eidx + N_EDGES;

    int* bcnt             = (int*)d_ws;                                   // [98*640]
    int* bst              = bcnt + N_CHUNKS * DSTRIDE;                    // [98*640]
    unsigned int* blkdata = (unsigned int*)(bst + N_CHUNKS * DSTRIDE);    // [625*1024]
    unsigned int* csr     = blkdata + (size_t)BIN_BLOCKS * EPB;           // [98*8192]
    int* off              = (int*)(csr + (size_t)N_CHUNKS * BINCAP);      // [100352]
    unsigned short* y     = (unsigned short*)(off + 100352);              // [N*128] bf16

    gcn_gemm_bin<<<GEMM_BLOCKS + BIN_BLOCKS, 256, 0, stream>>>(
        x, W, esrc, edst, y, blkdata, bcnt, bst);
    gcn_build<<<N_CHUNKS, 256, 0, stream>>>(blkdata, bcnt, bst, csr, off);
    gcn_agg  <<<N_NODES / 16, 256, 0, stream>>>(y, off, csr, bias, out);
}

// Round 16
// 91.387 us; speedup vs baseline: 1.1992x; 1.0921x over previous
//
#include <hip/hip_runtime.h>
#include <hip/hip_bf16.h>

constexpr int N_NODES = 100000;
constexpr int DIM     = 128;
constexpr int N_EDGES = 640000;

constexpr int CHUNK     = 1024;
constexpr int N_CHUNKS  = (N_NODES + CHUNK - 1) / CHUNK;   // 98
constexpr int BINCAP    = 8192;
constexpr int EPB       = 1024;
constexpr int SRC_BITS  = 17;
constexpr int SRC_MASK  = (1 << SRC_BITS) - 1;

constexpr int YNB = 32;                                    // nodes per gemm block

typedef __attribute__((ext_vector_type(4))) float        f32x4;
typedef __attribute__((ext_vector_type(8))) short        bf16x8;
typedef __attribute__((ext_vector_type(4))) unsigned int u32x4;

static __device__ inline unsigned short f2bf(float f) {
    __hip_bfloat16 h = __float2bfloat16(f);   // RNE
    return *reinterpret_cast<unsigned short*>(&h);
}
static __device__ inline float bf_lo(unsigned u) { return __uint_as_float(u << 16); }
static __device__ inline float bf_hi(unsigned u) { return __uint_as_float(u & 0xffff0000u); }

static __device__ inline bf16x8 pack8(f32x4 a, f32x4 b) {
    bf16x8 v;
    v[0] = (short)f2bf(a.x); v[1] = (short)f2bf(a.y);
    v[2] = (short)f2bf(a.z); v[3] = (short)f2bf(a.w);
    v[4] = (short)f2bf(b.x); v[5] = (short)f2bf(b.y);
    v[6] = (short)f2bf(b.z); v[7] = (short)f2bf(b.w);
    return v;
}

// ---------------------------------------------------------------------------
// 1) Dense GEMM: y = bf16( x @ W^T )  (no bias/relu here — applied in agg).
//    32 nodes/block. W staged f32->bf16 into LDS once per block (L2-hot).
//    Block 0 also zeroes the 98 bin cursors.
// ---------------------------------------------------------------------------
__global__ __launch_bounds__(256) void gcn_gemm_y(
    const float* __restrict__ x,
    const float* __restrict__ W,
    unsigned short* __restrict__ y,
    int* __restrict__ bincur)
{
    __shared__ unsigned short wl[DIM][DIM + 8];   // 34.8 KB

    const int tid = threadIdx.x;
    const int n0  = blockIdx.x * YNB;             // grid exact: 3125 blocks

    if (blockIdx.x == 0 && tid < 128) bincur[tid] = 0;

    // Stage W: 16384 f32 -> bf16 LDS, 64 elems/thread, coalesced 32B loads
    #pragma unroll
    for (int rep = 0; rep < 8; ++rep) {
        const int e   = rep * 2048 + tid * 8;
        const int row = e >> 7;
        const int col = e & 127;
        f32x4 a = *reinterpret_cast<const f32x4*>(W + e);
        f32x4 b = *reinterpret_cast<const f32x4*>(W + e + 4);
        *reinterpret_cast<bf16x8*>(&wl[row][col]) = pack8(a, b);
    }
    __syncthreads();

    const int w    = tid >> 6;
    const int lane = tid & 63;
    const int r    = lane & 15;
    const int g    = lane >> 4;
    const int rowt  = w & 1;                      // row-tile 0/1 (16 rows each)
    const int cbase = 4 * (w >> 1);               // c-groups 0..3 / 4..7

    // A-frags from global f32 x, converted in-register
    bf16x8 af[4];
    #pragma unroll
    for (int t = 0; t < 4; ++t) {
        const float* xp = x + (size_t)(n0 + 16 * rowt + r) * DIM + 32 * t + 8 * g;
        f32x4 a = *reinterpret_cast<const f32x4*>(xp);
        f32x4 b = *reinterpret_cast<const f32x4*>(xp + 4);
        af[t] = pack8(a, b);
    }

    #pragma unroll
    for (int cc = 0; cc < 4; ++cc) {
        const int c = cbase + cc;
        f32x4 acc = {0.f, 0.f, 0.f, 0.f};
        #pragma unroll
        for (int t = 0; t < 4; ++t) {
            bf16x8 wf = *reinterpret_cast<const bf16x8*>(&wl[16 * c + r][32 * t + 8 * g]);
            acc = __builtin_amdgcn_mfma_f32_16x16x32_bf16(af[t], wf, acc, 0, 0, 0);
        }
        #pragma unroll
        for (int q = 0; q < 4; ++q)
            y[(size_t)(n0 + 16 * rowt + 4 * g + q) * DIM + 16 * c + r] =
                f2bf(acc[q]);
    }
}

// ---------------------------------------------------------------------------
// 2) Bin pass: scatter edges into per-chunk regions (packed src|dstlocal).
// ---------------------------------------------------------------------------
__global__ __launch_bounds__(256) void gcn_bin(const int* __restrict__ src,
                                               const int* __restrict__ dst,
                                               int* __restrict__ bincur,
                                               unsigned int* __restrict__ bindata)
{
    __shared__ int bh[N_CHUNKS];
    __shared__ int btb[N_CHUNKS];

    const int t  = threadIdx.x;
    const int e0 = blockIdx.x * EPB + t * 4;

    if (t < N_CHUNKS) bh[t] = 0;
    __syncthreads();

    const int4 s4 = *reinterpret_cast<const int4*>(src + e0);
    const int4 d4 = *reinterpret_cast<const int4*>(dst + e0);

    int bin[4], pos[4];
    unsigned pv[4];
    const int ds[4] = {d4.x, d4.y, d4.z, d4.w};
    const int ss[4] = {s4.x, s4.y, s4.z, s4.w};
    #pragma unroll
    for (int q = 0; q < 4; ++q) {
        bin[q] = ds[q] >> 10;
        pv[q]  = (unsigned)ss[q] | ((unsigned)(ds[q] & (CHUNK - 1)) << SRC_BITS);
        pos[q] = atomicAdd(&bh[bin[q]], 1);
    }
    __syncthreads();

    if (t < N_CHUNKS) btb[t] = atomicAdd(&bincur[t], bh[t]);
    __syncthreads();

    #pragma unroll
    for (int q = 0; q < 4; ++q)
        bindata[(size_t)bin[q] * BINCAP + btb[bin[q]] + pos[q]] = pv[q];
}

// ---------------------------------------------------------------------------
// 3) Build pass: per-chunk LDS counting sort -> dense csr + off metadata.
// ---------------------------------------------------------------------------
__global__ __launch_bounds__(256) void gcn_build(const int* __restrict__ bincur,
                                                 unsigned int* __restrict__ bindata,
                                                 int* __restrict__ off)
{
    __shared__ unsigned stage[BINCAP];
    __shared__ int hist[CHUNK];
    __shared__ int s[256];

    const int c  = blockIdx.x;
    const int t  = threadIdx.x;
    const int nb = min(bincur[c], BINCAP);
    unsigned int* region = bindata + (size_t)c * BINCAP;

    for (int e = t; e < nb; e += 256) stage[e] = region[e];
    #pragma unroll
    for (int q = 0; q < 4; ++q) hist[t + 256 * q] = 0;
    __syncthreads();

    for (int e = t; e < nb; e += 256)
        atomicAdd(&hist[stage[e] >> SRC_BITS], 1);
    __syncthreads();

    int h0 = hist[4 * t + 0], h1 = hist[4 * t + 1];
    int h2 = hist[4 * t + 2], h3 = hist[4 * t + 3];
    s[t] = h0 + h1 + h2 + h3;
    __syncthreads();
    for (int d = 1; d < 256; d <<= 1) {
        int add = (t >= d) ? s[t - d] : 0;
        __syncthreads();
        s[t] += add;
        __syncthreads();
    }
    int excl = (t > 0) ? s[t - 1] : 0;

    const int st0 = excl;
    const int st1 = excl + h0;
    const int st2 = excl + h0 + h1;
    const int st3 = excl + h0 + h1 + h2;
    hist[4 * t + 0] = st0;  hist[4 * t + 1] = st1;
    hist[4 * t + 2] = st2;  hist[4 * t + 3] = st3;

    const int nbase = c * CHUNK;
    if (nbase + 4 * t + 0 < N_NODES) off[nbase + 4 * t + 0] = st0 | (h0 << 13);
    if (nbase + 4 * t + 1 < N_NODES) off[nbase + 4 * t + 1] = st1 | (h1 << 13);
    if (nbase + 4 * t + 2 < N_NODES) off[nbase + 4 * t + 2] = st2 | (h2 << 13);
    if (nbase + 4 * t + 3 < N_NODES) off[nbase + 4 * t + 3] = st3 | (h3 << 13);
    __syncthreads();

    for (int e = t; e < nb; e += 256) {
        unsigned v  = stage[e];
        int slot    = atomicAdd(&hist[v >> SRC_BITS], 1);
        region[slot] = v & SRC_MASK;
    }
}

// ---------------------------------------------------------------------------
// 4) Pure gather in y-space: out[n] = relu( sum(y[src])/max(deg,1) + y[n] + b ).
//    16 lanes/node, 16B/lane, 4-deep unroll. NO LDS, NO barrier.
// ---------------------------------------------------------------------------
static __device__ inline void acc8(float* acc, u32x4 v) {
    #pragma unroll
    for (int q = 0; q < 4; ++q) {
        unsigned u = v[q];
        acc[2 * q]     += bf_lo(u);
        acc[2 * q + 1] += bf_hi(u);
    }
}

__global__ __launch_bounds__(256) void gcn_agg(
    const unsigned short* __restrict__ y,
    const int* __restrict__ off,
    const unsigned int* __restrict__ csr,
    const float* __restrict__ bias,
    float* __restrict__ out)
{
    const int tid    = threadIdx.x;
    const int lane16 = tid & 15;
    const int n      = blockIdx.x * 16 + (tid >> 4);   // grid exact: 6250
    const int col8   = lane16 * 8;

    const int meta  = off[n];
    const int count = meta >> 13;
    int i           = (n >> 10) * BINCAP + (meta & (BINCAP - 1));
    const int end   = i + count;

    float acc[8];
    #pragma unroll
    for (int q = 0; q < 8; ++q) acc[q] = 0.0f;

    for (; i + 4 <= end; i += 4) {
        int s0 = csr[i], s1 = csr[i + 1], s2 = csr[i + 2], s3 = csr[i + 3];
        u32x4 v0 = *reinterpret_cast<const u32x4*>(y + (size_t)s0 * DIM + col8);
        u32x4 v1 = *reinterpret_cast<const u32x4*>(y + (size_t)s1 * DIM + col8);
        u32x4 v2 = *reinterpret_cast<const u32x4*>(y + (size_t)s2 * DIM + col8);
        u32x4 v3 = *reinterpret_cast<const u32x4*>(y + (size_t)s3 * DIM + col8);
        acc8(acc, v0); acc8(acc, v1); acc8(acc, v2); acc8(acc, v3);
    }
    for (; i < end; ++i) {
        u32x4 v = *reinterpret_cast<const u32x4*>(y + (size_t)csr[i] * DIM + col8);
        acc8(acc, v);
    }

    const float inv = 1.0f / fmaxf((float)count, 1.0f);
    const u32x4 yr = *reinterpret_cast<const u32x4*>(y + (size_t)n * DIM + col8);
    const f32x4 b0 = *reinterpret_cast<const f32x4*>(bias + col8);
    const f32x4 b1 = *reinterpret_cast<const f32x4*>(bias + col8 + 4);

    f32x4 o0, o1;
    o0.x = fmaxf(acc[0] * inv + bf_lo(yr[0]) + b0.x, 0.0f);
    o0.y = fmaxf(acc[1] * inv + bf_hi(yr[0]) + b0.y, 0.0f);
    o0.z = fmaxf(acc[2] * inv + bf_lo(yr[1]) + b0.z, 0.0f);
    o0.w = fmaxf(acc[3] * inv + bf_hi(yr[1]) + b0.w, 0.0f);
    o1.x = fmaxf(acc[4] * inv + bf_lo(yr[2]) + b1.x, 0.0f);
    o1.y = fmaxf(acc[5] * inv + bf_hi(yr[2]) + b1.y, 0.0f);
    o1.z = fmaxf(acc[6] * inv + bf_lo(yr[3]) + b1.z, 0.0f);
    o1.w = fmaxf(acc[7] * inv + bf_hi(yr[3]) + b1.w, 0.0f);

    *reinterpret_cast<f32x4*>(out + (size_t)n * DIM + col8)     = o0;
    *reinterpret_cast<f32x4*>(out + (size_t)n * DIM + col8 + 4) = o1;
}

// ---------------------------------------------------------------------------
extern "C" void kernel_launch(void* const* d_in, const int* in_sizes, int n_in,
                              void* d_out, int out_size, void* d_ws, size_t ws_size,
                              hipStream_t stream)
{
    const float* x    = (const float*)d_in[0];
    const int*   eidx = (const int*)d_in[1];
    const float* W    = (const float*)d_in[2];
    const float* bias = (const float*)d_in[3];
    float*       out  = (float*)d_out;

    const int* src = eidx;
    const int* dst = eidx + N_EDGES;

    int* bincur = (int*)d_ws;                               // [128]
    int* off    = bincur + 128;                             // [N]
    unsigned int* bindata = (unsigned int*)(off + 100352);  // [98*8192] -> becomes csr
    unsigned short* y = (unsigned short*)(bindata + (size_t)N_CHUNKS * BINCAP); // [N*128] bf16

    gcn_gemm_y<<<N_NODES / YNB, 256, 0, stream>>>(x, W, y, bincur);
    gcn_bin   <<<N_EDGES / EPB, 256, 0, stream>>>(src, dst, bincur, bindata);
    gcn_build <<<N_CHUNKS, 256, 0, stream>>>(bincur, bindata, off);
    gcn_agg   <<<N_NODES / 16, 256, 0, stream>>>(y, off, bindata, bias, out);
}